// Round 5
// baseline (55.311 us; speedup 1.0000x reference)
//
#include <hip/hip_runtime.h>
#include <math.h>

// Problem constants from the reference
#define BB 32
#define NN 8
#define TT 52
#define HH 224
#define WW 224
#define PP 100   // 10x10 local grid; point p: slot A = lane p (p<64), slot B = lane p-64 (p>=64)
#define WPB 4    // waves per block; each wave = one independent trajectory

__device__ __forceinline__ float rlane_f(float v, int l) {
    return __int_as_float(__builtin_amdgcn_readlane(__float_as_int(v), l));
}

__global__ __launch_bounds__(64 * WPB) void mapcoll_kernel(
    const float* __restrict__ x,        // (B,N,T,6)
    const float* __restrict__ dmap,     // (B,H,W)
    const float* __restrict__ extent,   // (B,3)
    const float* __restrict__ rfa,      // (B,3,3)
    float* __restrict__ out)            // (B,N)
{
    const int wv   = threadIdx.x >> 6;
    const int lane = threadIdx.x & 63;
    const int m    = blockIdx.x * WPB + wv;   // 0 .. B*N*T-1
    const int b    = m / (NN * TT);
    const int bn   = m / TT;                  // b*N + n

    __shared__ float s_qx[WPB][PP], s_qy[WPB][PP];   // per-wave regions, no cross-wave sync

    // ---- uniform per-trajectory scalars ----
    const float posx = x[m * 6 + 0];
    const float posy = x[m * 6 + 1];
    const float yaw  = x[m * 6 + 3];
    const float lwx  = extent[b * 3 + 0];
    const float lwy  = extent[b * 3 + 1];
    const float inv_diag = 1.0f / sqrtf(lwx * lwx + lwy * lwy);
    const float r00 = rfa[b*9+0], r01 = rfa[b*9+1], r02 = rfa[b*9+2];
    const float r10 = rfa[b*9+3], r11 = rfa[b*9+4], r12 = rfa[b*9+5];
    const float sy = __sinf(yaw);
    const float cy = __cosf(yaw);
    const float* __restrict__ map_b = dmap + (size_t)b * (HH * WW);

    // ---- per-lane footprint points (2 slots) ----
    const int iA = lane / 10, jA = lane - iA * 10;
    const int pB = lane + 64;
    const int iB = pB / 10,   jB = pB - iB * 10;
    const float lA = -0.5f + (float)iA * (1.0f / 9.0f);
    const float wA = -0.5f + (float)jA * (1.0f / 9.0f);
    const float lB = -0.5f + (float)iB * (1.0f / 9.0f);
    const float wB = -0.5f + (float)jB * (1.0f / 9.0f);

    const float p0A = lA * lwx, p1A = wA * lwy;
    const float p0B = lB * lwx, p1B = wB * lwy;
    const float axA = p0A * cy - p1A * sy + posx;
    const float ayA = p0A * sy + p1A * cy + posy;
    const float axB = p0B * cy - p1B * sy + posx;
    const float ayB = p0B * sy + p1B * cy + posy;

    // ---- rasterize + gather collision flags ----
    int clA = 0, clB = 0;
    {
        const float fx = axA * r00 + ayA * r01 + r02;
        const float fy = axA * r10 + ayA * r11 + r12;
        int ix = (int)fx, iy = (int)fy;
        ix = ix < 0 ? 0 : (ix > WW - 1 ? WW - 1 : ix);
        iy = iy < 0 ? 0 : (iy > HH - 1 ? HH - 1 : iy);
        clA = (map_b[iy * WW + ix] == 0.0f) ? 1 : 0;
    }
    if (lane < PP - 64) {   // 36 lanes own a B point
        const float fx = axB * r00 + ayB * r01 + r02;
        const float fy = axB * r10 + ayB * r11 + r12;
        int ix = (int)fx, iy = (int)fy;
        ix = ix < 0 ? 0 : (ix > WW - 1 ? WW - 1 : ix);
        iy = iy < 0 ? 0 : (iy > HH - 1 ? HH - 1 : iy);
        clB = (map_b[iy * WW + ix] == 0.0f) ? 1 : 0;
    }

    // ---- uniform masks / counts ----
    const unsigned long long cmA = __ballot(clA);
    const unsigned long long cmB = __ballot(clB);
    const int ncA   = __popcll(cmA);
    const int ncoll = ncA + __popcll(cmB);
    if (ncoll == 0 || ncoll == PP) return;   // overlap false -> contributes 0 (wave-independent exit)

    // ---- compact colliding q's to ranks 0..ncoll-1 (deterministic, per-wave LDS) ----
    const unsigned long long below = lane ? ((~0ull) >> (64 - lane)) : 0ull;
    if (clA) { const int r = __popcll(cmA & below);       s_qx[wv][r] = axA; s_qy[wv][r] = ayA; }
    if (clB) { const int r = ncA + __popcll(cmB & below); s_qx[wv][r] = axB; s_qy[wv][r] = ayB; }
    // Same-wave LDS write->read: drain LDS queue, then block compiler reordering.
    asm volatile("s_waitcnt lgkmcnt(0)" ::: "memory");
    __builtin_amdgcn_wave_barrier();

    // ---- broadcast-source values: t_p = |a_p|^2 + (coll ? 1e30 : 0) ----
    const float m2axA = -2.0f * axA, m2ayA = -2.0f * ayA;
    const float m2axB = -2.0f * axB, m2ayB = -2.0f * ayB;
    const float tAv = fmaf(axA, axA, ayA * ayA) + (clA ? 1e30f : 0.0f);
    const float tBv = fmaf(axB, axB, ayB * ayB) + (clB ? 1e30f : 0.0f);

    const float qx  = s_qx[wv][lane];        // garbage beyond ncoll, masked later
    const float qy  = s_qy[wv][lane];
    const float sqq = fmaf(qx, qx, qy * qy);

    // ---- min_p (t_p - 2*a_p.q), fully unrolled, constant-lane readlanes ----
    float md0 = 3.402823466e+38f, md1 = 3.402823466e+38f;
    float md2 = 3.402823466e+38f, md3 = 3.402823466e+38f;

#define PAIR(P, ACC) { \
        const float bx = ((P) < 64) ? rlane_f(m2axA, (P)) : rlane_f(m2axB, (P) - 64); \
        const float by = ((P) < 64) ? rlane_f(m2ayA, (P)) : rlane_f(m2ayB, (P) - 64); \
        const float bt = ((P) < 64) ? rlane_f(tAv,  (P))  : rlane_f(tBv,  (P) - 64); \
        ACC = fminf(ACC, fmaf(bx, qx, fmaf(by, qy, bt))); }

    #pragma unroll
    for (int p = 0; p < PP; p += 4) {
        PAIR(p + 0, md0)
        PAIR(p + 1, md1)
        PAIR(p + 2, md2)
        PAIR(p + 3, md3)
    }
#undef PAIR

    float mind2 = fminf(fminf(md0, md1), fminf(md2, md3)) + sqq;
    mind2 = fmaxf(mind2, 0.0f);
    const int nq0 = ncoll < 64 ? ncoll : 64;
    float loss = (lane < nq0) ? (1.0f - sqrtf(mind2) * inv_diag) : 0.0f;

    // ---- rare second q-row (ncoll > 64), uniform branch, rolled ----
    if (ncoll > 64) {
        float qx1 = 0.0f, qy1 = 0.0f;
        if (lane < PP - 64) { qx1 = s_qx[wv][64 + lane]; qy1 = s_qy[wv][64 + lane]; }
        const float sqq1 = fmaf(qx1, qx1, qy1 * qy1);
        float md = 3.402823466e+38f;
        for (int p = 0; p < 64; ++p) {
            const float bx = rlane_f(m2axA, p);
            const float by = rlane_f(m2ayA, p);
            const float bt = rlane_f(tAv, p);
            md = fminf(md, fmaf(bx, qx1, fmaf(by, qy1, bt)));
        }
        for (int p = 0; p < PP - 64; ++p) {
            const float bx = rlane_f(m2axB, p);
            const float by = rlane_f(m2ayB, p);
            const float bt = rlane_f(tBv, p);
            md = fminf(md, fmaf(bx, qx1, fmaf(by, qy1, bt)));
        }
        const float m2v = fmaxf(md + sqq1, 0.0f);
        loss += (lane < ncoll - 64) ? (1.0f - sqrtf(m2v) * inv_diag) : 0.0f;
    }

    // ---- wave reduce + one atomic per wave ----
    #pragma unroll
    for (int off = 32; off > 0; off >>= 1) loss += __shfl_down(loss, off);
    if (lane == 0) atomicAdd(&out[bn], loss);
}

extern "C" void kernel_launch(void* const* d_in, const int* in_sizes, int n_in,
                              void* d_out, int out_size, void* d_ws, size_t ws_size,
                              hipStream_t stream) {
    const float* x      = (const float*)d_in[0];
    const float* dmap   = (const float*)d_in[1];
    const float* extent = (const float*)d_in[2];
    const float* rfa    = (const float*)d_in[3];
    float* out = (float*)d_out;

    // Output must be zeroed every call (harness poisons once, never restores)
    hipMemsetAsync(out, 0, (size_t)out_size * sizeof(float), stream);

    const int M = BB * NN * TT;               // 13312 trajectories
    const int blocks = M / WPB;               // 3328 blocks x 4 independent waves
    mapcoll_kernel<<<blocks, 64 * WPB, 0, stream>>>(x, dmap, extent, rfa, out);
}

// Round 6
// 26.675 us; speedup vs baseline: 2.0735x; 2.0735x over previous
//
#include <hip/hip_runtime.h>
#include <math.h>

// Problem constants from the reference
#define BB 32
#define NN 8
#define TT 52
#define HH 224
#define WW 224
#define PP 100   // 10x10 local grid; point p: slot A = lane p (p<64), slot B = lane p-64 (p>=64)
#define WPB 4    // waves per block; each wave = one independent trajectory

__device__ __forceinline__ float rlane_f(float v, int l) {
    return __int_as_float(__builtin_amdgcn_readlane(__float_as_int(v), l));
}

__global__ __launch_bounds__(64 * WPB) void mapcoll_kernel(
    const float* __restrict__ x,        // (B,N,T,6)
    const float* __restrict__ dmap,     // (B,H,W)
    const float* __restrict__ extent,   // (B,3)
    const float* __restrict__ rfa,      // (B,3,3)
    float* __restrict__ row)            // (M) per-trajectory row_loss
{
    const int wv   = threadIdx.x >> 6;
    const int lane = threadIdx.x & 63;
    const int m    = blockIdx.x * WPB + wv;   // 0 .. B*N*T-1
    const int b    = m / (NN * TT);

    __shared__ float s_qx[WPB][PP], s_qy[WPB][PP];   // per-wave regions, no cross-wave sync

    // ---- uniform per-trajectory scalars ----
    const float posx = x[m * 6 + 0];
    const float posy = x[m * 6 + 1];
    const float yaw  = x[m * 6 + 3];
    const float lwx  = extent[b * 3 + 0];
    const float lwy  = extent[b * 3 + 1];
    const float inv_diag = 1.0f / sqrtf(lwx * lwx + lwy * lwy);
    const float r00 = rfa[b*9+0], r01 = rfa[b*9+1], r02 = rfa[b*9+2];
    const float r10 = rfa[b*9+3], r11 = rfa[b*9+4], r12 = rfa[b*9+5];
    const float sy = __sinf(yaw);
    const float cy = __cosf(yaw);
    const float* __restrict__ map_b = dmap + (size_t)b * (HH * WW);

    // ---- per-lane footprint points (2 slots) ----
    const int iA = lane / 10, jA = lane - iA * 10;
    const int pB = lane + 64;
    const int iB = pB / 10,   jB = pB - iB * 10;
    const float lA = -0.5f + (float)iA * (1.0f / 9.0f);
    const float wA = -0.5f + (float)jA * (1.0f / 9.0f);
    const float lB = -0.5f + (float)iB * (1.0f / 9.0f);
    const float wB = -0.5f + (float)jB * (1.0f / 9.0f);

    const float p0A = lA * lwx, p1A = wA * lwy;
    const float p0B = lB * lwx, p1B = wB * lwy;
    const float axA = p0A * cy - p1A * sy + posx;
    const float ayA = p0A * sy + p1A * cy + posy;
    const float axB = p0B * cy - p1B * sy + posx;
    const float ayB = p0B * sy + p1B * cy + posy;

    // ---- rasterize + gather collision flags ----
    int clA = 0, clB = 0;
    {
        const float fx = axA * r00 + ayA * r01 + r02;
        const float fy = axA * r10 + ayA * r11 + r12;
        int ix = (int)fx, iy = (int)fy;
        ix = ix < 0 ? 0 : (ix > WW - 1 ? WW - 1 : ix);
        iy = iy < 0 ? 0 : (iy > HH - 1 ? HH - 1 : iy);
        clA = (map_b[iy * WW + ix] == 0.0f) ? 1 : 0;
    }
    if (lane < PP - 64) {   // 36 lanes own a B point
        const float fx = axB * r00 + ayB * r01 + r02;
        const float fy = axB * r10 + ayB * r11 + r12;
        int ix = (int)fx, iy = (int)fy;
        ix = ix < 0 ? 0 : (ix > WW - 1 ? WW - 1 : ix);
        iy = iy < 0 ? 0 : (iy > HH - 1 ? HH - 1 : iy);
        clB = (map_b[iy * WW + ix] == 0.0f) ? 1 : 0;
    }

    // ---- uniform masks / counts ----
    const unsigned long long cmA = __ballot(clA);
    const unsigned long long cmB = __ballot(clB);
    const int ncA   = __popcll(cmA);
    const int ncoll = ncA + __popcll(cmB);
    if (ncoll == 0 || ncoll == PP) {          // overlap false -> row_loss = 0
        if (lane == 0) row[m] = 0.0f;         // ws is poisoned: must write every slot
        return;
    }

    // ---- compact colliding q's to ranks 0..ncoll-1 (deterministic, per-wave LDS) ----
    const unsigned long long below = lane ? ((~0ull) >> (64 - lane)) : 0ull;
    if (clA) { const int r = __popcll(cmA & below);       s_qx[wv][r] = axA; s_qy[wv][r] = ayA; }
    if (clB) { const int r = ncA + __popcll(cmB & below); s_qx[wv][r] = axB; s_qy[wv][r] = ayB; }
    // Same-wave LDS write->read: drain LDS queue, then block compiler reordering.
    asm volatile("s_waitcnt lgkmcnt(0)" ::: "memory");
    __builtin_amdgcn_wave_barrier();

    // ---- broadcast-source values: t_p = |a_p|^2 + (coll ? 1e30 : 0) ----
    const float m2axA = -2.0f * axA, m2ayA = -2.0f * ayA;
    const float m2axB = -2.0f * axB, m2ayB = -2.0f * ayB;
    const float tAv = fmaf(axA, axA, ayA * ayA) + (clA ? 1e30f : 0.0f);
    const float tBv = fmaf(axB, axB, ayB * ayB) + (clB ? 1e30f : 0.0f);

    const float qx  = s_qx[wv][lane];        // garbage beyond ncoll, masked later
    const float qy  = s_qy[wv][lane];
    const float sqq = fmaf(qx, qx, qy * qy);

    // ---- min_p (t_p - 2*a_p.q), fully unrolled, constant-lane readlanes ----
    float md0 = 3.402823466e+38f, md1 = 3.402823466e+38f;
    float md2 = 3.402823466e+38f, md3 = 3.402823466e+38f;

#define PAIR(P, ACC) { \
        const float bx = ((P) < 64) ? rlane_f(m2axA, (P)) : rlane_f(m2axB, (P) - 64); \
        const float by = ((P) < 64) ? rlane_f(m2ayA, (P)) : rlane_f(m2ayB, (P) - 64); \
        const float bt = ((P) < 64) ? rlane_f(tAv,  (P))  : rlane_f(tBv,  (P) - 64); \
        ACC = fminf(ACC, fmaf(bx, qx, fmaf(by, qy, bt))); }

    #pragma unroll
    for (int p = 0; p < PP; p += 4) {
        PAIR(p + 0, md0)
        PAIR(p + 1, md1)
        PAIR(p + 2, md2)
        PAIR(p + 3, md3)
    }
#undef PAIR

    float mind2 = fminf(fminf(md0, md1), fminf(md2, md3)) + sqq;
    mind2 = fmaxf(mind2, 0.0f);
    const int nq0 = ncoll < 64 ? ncoll : 64;
    float loss = (lane < nq0) ? (1.0f - sqrtf(mind2) * inv_diag) : 0.0f;

    // ---- rare second q-row (ncoll > 64), uniform branch, rolled ----
    if (ncoll > 64) {
        float qx1 = 0.0f, qy1 = 0.0f;
        if (lane < PP - 64) { qx1 = s_qx[wv][64 + lane]; qy1 = s_qy[wv][64 + lane]; }
        const float sqq1 = fmaf(qx1, qx1, qy1 * qy1);
        float md = 3.402823466e+38f;
        for (int p = 0; p < 64; ++p) {
            const float bx = rlane_f(m2axA, p);
            const float by = rlane_f(m2ayA, p);
            const float bt = rlane_f(tAv, p);
            md = fminf(md, fmaf(bx, qx1, fmaf(by, qy1, bt)));
        }
        for (int p = 0; p < PP - 64; ++p) {
            const float bx = rlane_f(m2axB, p);
            const float by = rlane_f(m2ayB, p);
            const float bt = rlane_f(tBv, p);
            md = fminf(md, fmaf(bx, qx1, fmaf(by, qy1, bt)));
        }
        const float m2v = fmaxf(md + sqq1, 0.0f);
        loss += (lane < ncoll - 64) ? (1.0f - sqrtf(m2v) * inv_diag) : 0.0f;
    }

    // ---- wave reduce + ONE plain store per wave (no atomics) ----
    #pragma unroll
    for (int off = 32; off > 0; off >>= 1) loss += __shfl_down(loss, off);
    if (lane == 0) row[m] = loss;
}

// Sum 52 per-t row losses into each of the 256 (b,n) outputs. Writes ALL of
// d_out unconditionally -> no memset needed, deterministic order.
__global__ __launch_bounds__(64) void reduce_kernel(
    const float* __restrict__ row,      // (M)
    float* __restrict__ out)            // (B*N)
{
    const int bn   = blockIdx.x;        // 0..255
    const int lane = threadIdx.x;
    float v = (lane < TT) ? row[bn * TT + lane] : 0.0f;
    #pragma unroll
    for (int off = 32; off > 0; off >>= 1) v += __shfl_down(v, off);
    if (lane == 0) out[bn] = v;
}

extern "C" void kernel_launch(void* const* d_in, const int* in_sizes, int n_in,
                              void* d_out, int out_size, void* d_ws, size_t ws_size,
                              hipStream_t stream) {
    const float* x      = (const float*)d_in[0];
    const float* dmap   = (const float*)d_in[1];
    const float* extent = (const float*)d_in[2];
    const float* rfa    = (const float*)d_in[3];
    float* out = (float*)d_out;
    float* row = (float*)d_ws;          // 13312 floats = 53 KB scratch

    const int M = BB * NN * TT;               // 13312 trajectories
    const int blocks = M / WPB;               // 3328 blocks x 4 independent waves
    mapcoll_kernel<<<blocks, 64 * WPB, 0, stream>>>(x, dmap, extent, rfa, row);
    reduce_kernel<<<BB * NN, 64, 0, stream>>>(row, out);
}

// Round 7
// 16.233 us; speedup vs baseline: 3.4073x; 1.6432x over previous
//
#include <hip/hip_runtime.h>
#include <math.h>

// Problem constants from the reference
#define BB 32
#define NN 8
#define TT 52
#define HH 224
#define WW 224
#define PP 100   // 10x10 local grid; point p: slot A = lane p (p<64), slot B = lane p-64 (p>=64)
#define WPB 4    // waves per block; each wave = one independent trajectory

__global__ __launch_bounds__(64 * WPB) void mapcoll_kernel(
    const float* __restrict__ x,        // (B,N,T,6)
    const float* __restrict__ dmap,     // (B,H,W)
    const float* __restrict__ extent,   // (B,3)
    const float* __restrict__ rfa,      // (B,3,3)
    float* __restrict__ row)            // (M) per-trajectory row_loss
{
    const int wv   = threadIdx.x >> 6;
    const int lane = threadIdx.x & 63;
    const int m    = blockIdx.x * WPB + wv;   // 0 .. B*N*T-1
    const int b    = m / (NN * TT);

    // ---- uniform per-trajectory scalars ----
    const float posx = x[m * 6 + 0];
    const float posy = x[m * 6 + 1];
    const float yaw  = x[m * 6 + 3];
    const float lwx  = extent[b * 3 + 0];
    const float lwy  = extent[b * 3 + 1];
    const float inv_diag = 1.0f / sqrtf(lwx * lwx + lwy * lwy);
    const float r00 = rfa[b*9+0], r01 = rfa[b*9+1], r02 = rfa[b*9+2];
    const float r10 = rfa[b*9+3], r11 = rfa[b*9+4], r12 = rfa[b*9+5];
    const float sny = __sinf(yaw);
    const float csy = __cosf(yaw);
    const float* __restrict__ map_b = dmap + (size_t)b * (HH * WW);

    // Rigid-motion invariance: |a_p - a_q|^2 = ((i_p-i_q)*sx)^2 + ((j_p-j_q)*sy)^2
    const float sx  = lwx * (1.0f / 9.0f);
    const float sy  = lwy * (1.0f / 9.0f);
    const float sy2 = sy * sy;

    // ---- per-lane footprint points (2 slots) ----
    const int iA = lane / 10, jA = lane - iA * 10;
    const int pB = lane + 64;
    const int iB = pB / 10,   jB = pB - iB * 10;
    const float lA = -0.5f + (float)iA * (1.0f / 9.0f);
    const float wA = -0.5f + (float)jA * (1.0f / 9.0f);
    const float lB = -0.5f + (float)iB * (1.0f / 9.0f);
    const float wB = -0.5f + (float)jB * (1.0f / 9.0f);

    const float p0A = lA * lwx, p1A = wA * lwy;
    const float p0B = lB * lwx, p1B = wB * lwy;
    const float axA = p0A * csy - p1A * sny + posx;
    const float ayA = p0A * sny + p1A * csy + posy;
    const float axB = p0B * csy - p1B * sny + posx;
    const float ayB = p0B * sny + p1B * csy + posy;

    // ---- rasterize + gather collision flags ----
    int clA = 0, clB = 0;
    {
        const float fx = axA * r00 + ayA * r01 + r02;
        const float fy = axA * r10 + ayA * r11 + r12;
        int ix = (int)fx, iy = (int)fy;
        ix = ix < 0 ? 0 : (ix > WW - 1 ? WW - 1 : ix);
        iy = iy < 0 ? 0 : (iy > HH - 1 ? HH - 1 : iy);
        clA = (map_b[iy * WW + ix] == 0.0f) ? 1 : 0;
    }
    if (lane < PP - 64) {   // 36 lanes own a B point
        const float fx = axB * r00 + ayB * r01 + r02;
        const float fy = axB * r10 + ayB * r11 + r12;
        int ix = (int)fx, iy = (int)fy;
        ix = ix < 0 ? 0 : (ix > WW - 1 ? WW - 1 : ix);
        iy = iy < 0 ? 0 : (iy > HH - 1 ? HH - 1 : iy);
        clB = (map_b[iy * WW + ix] == 0.0f) ? 1 : 0;
    }

    // ---- uniform masks / counts ----
    const unsigned long long cmA = __ballot(clA);
    const unsigned long long cmB = __ballot(clB);
    const int ncoll = __popcll(cmA) + __popcll(cmB);
    if (ncoll == 0 || ncoll == PP) {          // overlap false -> row_loss = 0
        if (lane == 0) row[m] = 0.0f;         // ws is poisoned: must write every slot
        return;
    }

    // ---- 10-bit FREE-column mask per grid row (wave-uniform -> SALU) ----
    const unsigned long long fA = ~cmA;                          // points 0..63
    const unsigned long long fB = (~cmB) & ((1ull << 36) - 1ull);// points 64..99
    unsigned rows[10], revs[10];
    #pragma unroll
    for (int r = 0; r < 6; ++r) rows[r] = (unsigned)((fA >> (10 * r)) & 0x3FFull);
    rows[6] = (unsigned)(((fA >> 60) | (fB << 4)) & 0x3FFull);
    #pragma unroll
    for (int r = 7; r < 10; ++r) rows[r] = (unsigned)((fB >> (10 * r - 64)) & 0x3FFull);
    #pragma unroll
    for (int r = 0; r < 10; ++r) revs[r] = __brev(rows[r]) >> 22;  // 10-bit reverse

    // min over free p of d2, via per-row nearest-free-column (one ctz per row).
    // Empty row -> marker bit 25 -> d=25 -> 625*sy2 >= 30.8 > max real d2 (~27).
    auto slot_min = [&](int iq, int jq) -> float {
        const int invj = 9 - jq;
        float di = (float)iq * sx;
        float mind2 = 1e30f;
        #pragma unroll
        for (int r = 0; r < 10; ++r) {
            const unsigned t = (rows[r] >> jq) | (revs[r] >> invj) | (1u << 25);
            const unsigned d = __builtin_ctz(t);        // nearest free |dj| in row
            const float d2f = (float)(d * d);
            mind2 = fminf(mind2, fmaf(di, di, d2f * sy2));
            di -= sx;                                    // di = (iq - r) * sx
        }
        return mind2;
    };

    float loss = 0.0f;
    {
        const float mA = slot_min(iA, jA);
        loss += clA ? (1.0f - sqrtf(mA) * inv_diag) : 0.0f;
    }
    {
        const float mB = slot_min(iB, jB);
        loss += clB ? (1.0f - sqrtf(mB) * inv_diag) : 0.0f;
    }

    // ---- wave reduce + ONE plain store per wave (no atomics) ----
    #pragma unroll
    for (int off = 32; off > 0; off >>= 1) loss += __shfl_down(loss, off);
    if (lane == 0) row[m] = loss;
}

// Sum 52 per-t row losses into each of the 256 (b,n) outputs. Writes ALL of
// d_out unconditionally -> no memset needed, deterministic order.
__global__ __launch_bounds__(64) void reduce_kernel(
    const float* __restrict__ row,      // (M)
    float* __restrict__ out)            // (B*N)
{
    const int bn   = blockIdx.x;        // 0..255
    const int lane = threadIdx.x;
    float v = (lane < TT) ? row[bn * TT + lane] : 0.0f;
    #pragma unroll
    for (int off = 32; off > 0; off >>= 1) v += __shfl_down(v, off);
    if (lane == 0) out[bn] = v;
}

extern "C" void kernel_launch(void* const* d_in, const int* in_sizes, int n_in,
                              void* d_out, int out_size, void* d_ws, size_t ws_size,
                              hipStream_t stream) {
    const float* x      = (const float*)d_in[0];
    const float* dmap   = (const float*)d_in[1];
    const float* extent = (const float*)d_in[2];
    const float* rfa    = (const float*)d_in[3];
    float* out = (float*)d_out;
    float* row = (float*)d_ws;          // 13312 floats = 53 KB scratch

    const int M = BB * NN * TT;               // 13312 trajectories
    const int blocks = M / WPB;               // 3328 blocks x 4 independent waves
    mapcoll_kernel<<<blocks, 64 * WPB, 0, stream>>>(x, dmap, extent, rfa, row);
    reduce_kernel<<<BB * NN, 64, 0, stream>>>(row, out);
}

// Round 8
// 14.606 us; speedup vs baseline: 3.7869x; 1.1114x over previous
//
#include <hip/hip_runtime.h>
#include <math.h>

// Problem constants from the reference
#define BB 32
#define NN 8
#define TT 52
#define HH 224
#define WW 224
#define PP 100    // 10x10 local grid; point p: slot A = lane p (p<64), slot B = lane p-64
#define NWAVE 13  // waves per block; block = one (b,n) output
#define KPT 4     // trajectories (t) per wave: 13*4 = 52 = TT

__global__ __launch_bounds__(NWAVE * 64) void mapcoll_fused(
    const float* __restrict__ x,        // (B,N,T,6)
    const float* __restrict__ dmap,     // (B,H,W)
    const float* __restrict__ extent,   // (B,3)
    const float* __restrict__ rfa,      // (B,3,3)
    float* __restrict__ out)            // (B*N)
{
    const int bn   = blockIdx.x;        // 0..255
    const int b    = bn >> 3;           // NN == 8
    const int wv   = threadIdx.x >> 6;
    const int lane = threadIdx.x & 63;

    __shared__ float s_part[NWAVE];

    // ---- per-b uniforms (hoisted: constant across all 52 t's) ----
    const float lwx = extent[b * 3 + 0];
    const float lwy = extent[b * 3 + 1];
    const float inv_diag = 1.0f / sqrtf(lwx * lwx + lwy * lwy);
    const float r00 = rfa[b*9+0], r01 = rfa[b*9+1], r02 = rfa[b*9+2];
    const float r10 = rfa[b*9+3], r11 = rfa[b*9+4], r12 = rfa[b*9+5];
    const float* __restrict__ map_b = dmap + (size_t)b * (HH * WW);
    // Rigid-motion invariance: |a_p - a_q|^2 = ((i_p-i_q)*sx)^2 + ((j_p-j_q)*sy)^2
    const float sx  = lwx * (1.0f / 9.0f);
    const float sy  = lwy * (1.0f / 9.0f);
    const float sy2 = sy * sy;

    // ---- per-lane footprint geometry (t-independent) ----
    const int iA = lane / 10, jA = lane - iA * 10;
    const int pB = lane + 64;
    const int iB = pB / 10,   jB = pB - iB * 10;
    const float p0A = (-0.5f + (float)iA * (1.0f/9.0f)) * lwx;
    const float p1A = (-0.5f + (float)jA * (1.0f/9.0f)) * lwy;
    const float p0B = (-0.5f + (float)iB * (1.0f/9.0f)) * lwx;
    const float p1B = (-0.5f + (float)jB * (1.0f/9.0f)) * lwy;
    const bool hasB = (lane < PP - 64);   // 36 lanes own a B point

    // ---- phase 1: transform + rasterize + ISSUE all 2*KPT gathers ----
    float vA[KPT], vB[KPT];
    #pragma unroll
    for (int k = 0; k < KPT; ++k) {
        const int m = bn * TT + wv * KPT + k;
        const float posx = x[m * 6 + 0];      // wave-uniform -> scalar loads
        const float posy = x[m * 6 + 1];
        const float yaw  = x[m * 6 + 3];
        const float sn = __sinf(yaw), cs = __cosf(yaw);
        const float axA = p0A * cs - p1A * sn + posx;
        const float ayA = p0A * sn + p1A * cs + posy;
        {
            const float fx = axA * r00 + ayA * r01 + r02;
            const float fy = axA * r10 + ayA * r11 + r12;
            int ix = (int)fx, iy = (int)fy;    // trunc cast, then clip (ref semantics)
            ix = ix < 0 ? 0 : (ix > WW - 1 ? WW - 1 : ix);
            iy = iy < 0 ? 0 : (iy > HH - 1 ? HH - 1 : iy);
            vA[k] = map_b[iy * WW + ix];
        }
        vB[k] = 1.0f;                          // lanes without B point: "free"
        if (hasB) {
            const float axB = p0B * cs - p1B * sn + posx;
            const float ayB = p0B * sn + p1B * cs + posy;
            const float fx = axB * r00 + ayB * r01 + r02;
            const float fy = axB * r10 + ayB * r11 + r12;
            int ix = (int)fx, iy = (int)fy;
            ix = ix < 0 ? 0 : (ix > WW - 1 ? WW - 1 : ix);
            iy = iy < 0 ? 0 : (iy > HH - 1 ? HH - 1 : iy);
            vB[k] = map_b[iy * WW + ix];
        }
    }

    // ---- phase 2: masks + per-row nearest-free-column min ----
    float acc = 0.0f;
    #pragma unroll
    for (int k = 0; k < KPT; ++k) {
        const int clA = (vA[k] == 0.0f) ? 1 : 0;   // offroad==1 <=> drv==0 ({0,1} map)
        const int clB = (vB[k] == 0.0f) ? 1 : 0;
        const unsigned long long cmA = __ballot(clA);
        const unsigned long long cmB = __ballot(clB);
        const int ncoll = __popcll(cmA) + __popcll(cmB);
        if (ncoll == 0 || ncoll == PP) continue;    // overlap false -> contributes 0

        // 10-bit FREE-column mask per grid row (wave-uniform -> SALU)
        const unsigned long long fA = ~cmA;                           // points 0..63
        const unsigned long long fB = (~cmB) & ((1ull << 36) - 1ull); // points 64..99
        unsigned rows[10], revs[10];
        #pragma unroll
        for (int r = 0; r < 6; ++r) rows[r] = (unsigned)((fA >> (10 * r)) & 0x3FFull);
        rows[6] = (unsigned)(((fA >> 60) | (fB << 4)) & 0x3FFull);
        #pragma unroll
        for (int r = 7; r < 10; ++r) rows[r] = (unsigned)((fB >> (10 * r - 64)) & 0x3FFull);
        #pragma unroll
        for (int r = 0; r < 10; ++r) revs[r] = __brev(rows[r]) >> 22;   // 10-bit reverse

        // Empty row -> marker bit 25 -> d=25 -> 625*sy2 >= 30.8 > max real d2 (~26.9)
        {   // slot A (every lane owns one)
            const int invj = 9 - jA;
            float di = (float)iA * sx;
            float mind2 = 1e30f;
            #pragma unroll
            for (int r = 0; r < 10; ++r) {
                const unsigned t = (rows[r] >> jA) | (revs[r] >> invj) | (1u << 25);
                const unsigned d = __builtin_ctz(t);
                mind2 = fminf(mind2, fmaf(di, di, (float)(d * d) * sy2));
                di -= sx;
            }
            acc += clA ? (1.0f - sqrtf(mind2) * inv_diag) : 0.0f;
        }
        {   // slot B (lanes 0..35); clB==0 elsewhere so result is masked anyway
            const int invj = 9 - jB;
            float di = (float)iB * sx;
            float mind2 = 1e30f;
            #pragma unroll
            for (int r = 0; r < 10; ++r) {
                const unsigned t = (rows[r] >> jB) | (revs[r] >> invj) | (1u << 25);
                const unsigned d = __builtin_ctz(t);
                mind2 = fminf(mind2, fmaf(di, di, (float)(d * d) * sy2));
                di -= sx;
            }
            acc += clB ? (1.0f - sqrtf(mind2) * inv_diag) : 0.0f;
        }
    }

    // ---- wave reduce -> LDS -> block reduce -> single store ----
    #pragma unroll
    for (int off = 32; off > 0; off >>= 1) acc += __shfl_down(acc, off);
    if (lane == 0) s_part[wv] = acc;
    __syncthreads();
    if (threadIdx.x < 64) {
        float v = (lane < NWAVE) ? s_part[lane] : 0.0f;
        v += __shfl_down(v, 8);
        v += __shfl_down(v, 4);
        v += __shfl_down(v, 2);
        v += __shfl_down(v, 1);
        if (lane == 0) out[bn] = v;   // every output written -> no memset needed
    }
}

extern "C" void kernel_launch(void* const* d_in, const int* in_sizes, int n_in,
                              void* d_out, int out_size, void* d_ws, size_t ws_size,
                              hipStream_t stream) {
    const float* x      = (const float*)d_in[0];
    const float* dmap   = (const float*)d_in[1];
    const float* extent = (const float*)d_in[2];
    const float* rfa    = (const float*)d_in[3];
    float* out = (float*)d_out;

    mapcoll_fused<<<BB * NN, NWAVE * 64, 0, stream>>>(x, dmap, extent, rfa, out);
}